// Round 6
// baseline (274.136 us; speedup 1.0000x reference)
//
#include <hip/hip_runtime.h>
#include <math.h>

#define SS 2048
#define EE 1024

using bf16x8 = __attribute__((ext_vector_type(8))) short;
using f32x4  = __attribute__((ext_vector_type(4))) float;

// RTNE (prep only, cold)
__device__ inline short f2bf(float x) {
    unsigned u = __builtin_bit_cast(unsigned, x);
    return (short)((u + 0x7fffu + ((u >> 16) & 1u)) >> 16);
}
// round-half-up, 2 VALU
__device__ inline short f2bf_r(float x) {
    return (short)((__builtin_bit_cast(unsigned, x) + 0x8000u) >> 16);
}
// pack 2 floats -> 2 bf16 in one dword: 2 adds + 1 v_perm
__device__ inline unsigned pk_bf16(float a, float b) {
    unsigned ua = __builtin_bit_cast(unsigned, a) + 0x8000u;
    unsigned ub = __builtin_bit_cast(unsigned, b) + 0x8000u;
    return __builtin_amdgcn_perm(ub, ua, 0x07060302u);
}
// async global->LDS, 16B per lane; LDS dest = wave-uniform base + lane*16
__device__ inline void gl16(const short* g, short* l) {
    __builtin_amdgcn_global_load_lds(
        (const __attribute__((address_space(1))) void*)g,
        (__attribute__((address_space(3))) void*)l, 16, 0, 0);
}

// ---------- weight prep + rope table + q/kv fp32->bf16 conversion ----------
// blocks 0..8191: convert q|kv (16.7M fp32) -> Ab bf16 (rows 0..8191 q, 8192..16383 kv)
// blocks 8192..9215: weight prep + rope table (as before)
__global__ __launch_bounds__(256) void prep_weights(const float* __restrict__ q,
                                                    const float* __restrict__ kv,
                                                    const float* __restrict__ Wq,
                                                    const float* __restrict__ Wk,
                                                    const float* __restrict__ Wv,
                                                    const float* __restrict__ Wo,
                                                    short* __restrict__ Ab,
                                                    short* __restrict__ Wall,
                                                    short* __restrict__ Wo4,
                                                    float2* __restrict__ RT) {
    if (blockIdx.x < 8192) {
        int gt = blockIdx.x * 256 + threadIdx.x;   // 2,097,152 threads x 8 elems
        size_t e0 = (size_t)gt * 8;
        const float* src = (e0 < 8388608) ? (q + e0) : (kv + (e0 - 8388608));
        float4 v0 = *(const float4*)src;
        float4 v1 = *(const float4*)(src + 4);
        int4 u;
        u.x = pk_bf16(v0.x, v0.y);
        u.y = pk_bf16(v0.z, v0.w);
        u.z = pk_bf16(v1.x, v1.y);
        u.w = pk_bf16(v1.z, v1.w);
        *(int4*)&Ab[e0] = u;
        return;
    }
    int idx = (blockIdx.x - 8192) * 256 + threadIdx.x;   // 262144 = 256 c * 1024 e
    int c = idx >> 10, e = idx & 1023;
    int h = c >> 6, d = c & 63;
    const float* p = Wq + (size_t)e * 1024 + h * 256 + d;   // Wq[e][h*4+g][d]
    Wall[(size_t)c * 1024 + e] = f2bf(0.18033688011112042f * (p[0] + p[64] + p[128] + p[192]));
    Wall[(size_t)(256 + c) * 1024 + e] = f2bf(Wk[(size_t)e * 256 + c]);
    Wall[(size_t)(512 + c) * 1024 + e] = f2bf(Wv[(size_t)e * 256 + c]);
    Wo4[(size_t)e * 256 + c] = f2bf(0.25f * Wo[(size_t)d * 1024 + e]);
    if (idx < 65536) {
        int s = idx >> 5, ii = idx & 31;
        float freq = __expf(-(float)ii * (9.210340371976184f / 32.0f));
        float sn, cs;
        sincosf((float)s * freq, &sn, &cs);
        RT[idx] = (float2){cs, sn};
    }
}

// ---------- fused Q/K/V projection; pure bf16 GEMM w/ global_load_lds staging ----------
// BM=128, BN=64, BK=64; linear LDS (m97 structure); rope/V epilogues on retired LDS.
__global__ __launch_bounds__(256) void proj_kernel(const short* __restrict__ Ab,
                                                   const short* __restrict__ Wall,
                                                   const float2* __restrict__ RT,
                                                   short* __restrict__ Qb,
                                                   short* __restrict__ Kb,
                                                   short* __restrict__ Vt) {
    __shared__ alignas(16) short SMEM[128 * 64 + 64 * 64];   // As[128][64] | Bs[64][64]
    short (*As)[64] = (short (*)[64])SMEM;
    short (*Bs)[64] = (short (*)[64])(SMEM + 128 * 64);
    int tid = threadIdx.x;
    int wave = tid >> 6, lane = tid & 63, quad = lane >> 4, c16 = lane & 15;
    int wm = wave >> 1, wn = wave & 1;
    int m0 = blockIdx.x * 128, n0 = blockIdx.y * 64;
    const short* A = Ab + ((n0 < 256) ? 0 : (size_t)8388608);   // q rows | kv rows

    int lr = lane >> 3, lc = lane & 7;     // lane -> (row-in-8, 16B-chunk)
    f32x4 acc[4][2];
    #pragma unroll
    for (int i = 0; i < 4; i++)
        #pragma unroll
        for (int j = 0; j < 2; j++) acc[i][j] = (f32x4){0.f, 0.f, 0.f, 0.f};

    for (int k0 = 0; k0 < 1024; k0 += 64) {
        __syncthreads();   // prev tile's ds_reads complete
        // A tile: 128x64 bf16 = 16KB -> 16 wave-segments of 1KB; wave handles 4
        #pragma unroll
        for (int i = 0; i < 4; i++) {
            int seg = wave * 4 + i;
            int r = seg * 8 + lr;
            gl16(&A[(size_t)(m0 + r) * 1024 + k0 + lc * 8], &As[seg * 8][0]);
        }
        // B tile: 64x64 bf16 = 8KB -> 8 segments; wave handles 2
        #pragma unroll
        for (int i = 0; i < 2; i++) {
            int seg = wave * 2 + i;
            int r = seg * 8 + lr;
            gl16(&Wall[(size_t)(n0 + r) * 1024 + k0 + lc * 8], &Bs[seg * 8][0]);
        }
        __syncthreads();   // vmcnt(0) drained: tile ready
        #pragma unroll
        for (int ks = 0; ks < 64; ks += 32) {
            bf16x8 af[4], bfr[2];
            #pragma unroll
            for (int mt = 0; mt < 4; mt++)
                af[mt] = *(const bf16x8*)&As[wm * 64 + mt * 16 + c16][ks + quad * 8];
            #pragma unroll
            for (int nt = 0; nt < 2; nt++)
                bfr[nt] = *(const bf16x8*)&Bs[wn * 32 + nt * 16 + c16][ks + quad * 8];
            #pragma unroll
            for (int mt = 0; mt < 4; mt++)
                #pragma unroll
                for (int nt = 0; nt < 2; nt++)
                    acc[mt][nt] = __builtin_amdgcn_mfma_f32_16x16x32_bf16(
                        af[mt], bfr[nt], acc[mt][nt], 0, 0, 0);
        }
    }
    __syncthreads();   // all MFMA LDS reads done before epilogue reuses SMEM
    if (n0 < 512) {
        // Q or K: rope in regs -> As[128][64] bf16 -> coalesced row-major stores
        #pragma unroll
        for (int mt = 0; mt < 4; mt++) {
            #pragma unroll
            for (int nt = 0; nt < 2; nt++) {
                int cl = wn * 32 + nt * 16 + c16;       // local col 0..63
                int ii = cl >> 1;                        // n0 multiple of 64
                float sgn = (lane & 1) ? 1.0f : -1.0f;
                f32x4 v = acc[mt][nt];
                #pragma unroll
                for (int r = 0; r < 4; r++) {
                    int rl = wm * 64 + mt * 16 + quad * 4 + r;   // local row
                    float2 cs = RT[((m0 + rl) & (SS - 1)) * 32 + ii];
                    float other = __shfl_xor(v[r], 1);
                    As[rl][cl] = f2bf_r(v[r] * cs.x + sgn * cs.y * other);
                }
            }
        }
        __syncthreads();
        short* dstb = (n0 < 256) ? Qb : Kb;
        int nc0 = n0 & 255;
        #pragma unroll
        for (int i = 0; i < 4; i++) {
            int id = i * 256 + tid, r = id >> 3, ch = id & 7;
            *(int4*)&dstb[(size_t)(m0 + r) * 256 + nc0 + ch * 8] =
                *(const int4*)&As[r][ch * 8];
        }
    } else {
        // V: transpose via LDS -> Vt[(b*256+c)][s] coalesced along s
        short (*Lt)[136] = (short(*)[136])SMEM;    // 64 c x (128 s + pad) = 17408B <= 24576B
        #pragma unroll
        for (int mt = 0; mt < 4; mt++) {
            #pragma unroll
            for (int nt = 0; nt < 2; nt++) {
                int cl = wn * 32 + nt * 16 + c16;
                int sl = wm * 64 + mt * 16 + quad * 4;
                f32x4 v = acc[mt][nt];
                uint2 u;
                u.x = pk_bf16(v[0], v[1]);
                u.y = pk_bf16(v[2], v[3]);
                *(uint2*)&Lt[cl][sl] = u;
            }
        }
        __syncthreads();
        int b = m0 >> 11, s0 = m0 & (SS - 1), c0 = n0 - 512;
        #pragma unroll
        for (int i = 0; i < 4; i++) {
            int id = i * 256 + tid, c = id >> 4, ch = id & 15;
            *(int4*)&Vt[((size_t)(b * 256 + c0 + c)) * SS + s0 + ch * 8] =
                *(const int4*)&Lt[c][ch * 8];
        }
    }
}

// ---------- MFMA flash attention: BARRIER-FREE main loop, K/V/Q direct from L1/L2 ----------
// 8 waves: wave = (rq = wave&3 -> 16-row q slice, kh = wave>>2 -> K half of 1024 keys).
// MFMA fragments are 16B row-chunks of Qb/Kb/Vt -> per-lane global int4 loads, no LDS
// staging, no barriers in the k-loop. Only the wave-private P tile lives in LDS.
// In-block kh-combine (3 barriers) at the end; output bf16 Ob[b,s,h*64+d].
__global__ __launch_bounds__(512, 4) void attn_kernel(const short* __restrict__ Qb,
                                                      const short* __restrict__ Kb,
                                                      const short* __restrict__ Vt,
                                                      short* __restrict__ Ob) {
    __shared__ alignas(16) short Psb[8][16][72];   // per-wave P tiles; Ox aliases in epilogue
    __shared__ alignas(16) short Otb[64][72];      // epilogue: combined bf16 out
    __shared__ float Lxb[64];                      // epilogue: kh=1 lsums
    int tid = threadIdx.x;
    int wave = tid >> 6, lane = tid & 63, quad = lane >> 4, c16 = lane & 15;
    int rq = wave & 3, kh = wave >> 2;
    int qt = blockIdx.x, bh = blockIdx.y;
    int q0 = qt * 64;
    size_t qkbase = (size_t)(bh >> 2) * SS * 256 + (bh & 3) * 64;
    size_t vtbase = (size_t)(bh * 64) * SS;

    // Q fragments: direct per-lane global loads (row q0+rq*16+c16, 16B chunk at quad*8)
    const short* qrow = Qb + qkbase + (size_t)(q0 + rq * 16 + c16) * 256 + quad * 8;
    bf16x8 aq0 = *(const bf16x8*)qrow;
    bf16x8 aq1 = *(const bf16x8*)(qrow + 32);

    short (*Ps)[72] = Psb[wave];

    // per-lane K/V fragment base pointers for this wave's kh half
    const short* kp = Kb + qkbase + (size_t)(kh * 1024 + c16) * 256 + quad * 8;
    const short* vp = Vt + vtbase + (size_t)c16 * SS + kh * 1024 + quad * 8;

    float lsum[4] = {0.f, 0.f, 0.f, 0.f};
    f32x4 o[4];
    #pragma unroll
    for (int dt = 0; dt < 4; dt++) o[dt] = (f32x4){0.f, 0.f, 0.f, 0.f};

    for (int kt = 0; kt < 16; kt++) {
        int a0 = kt * 64;
        f32x4 sv[4];
        #pragma unroll
        for (int nt = 0; nt < 4; nt++) sv[nt] = (f32x4){0.f, 0.f, 0.f, 0.f};
        #pragma unroll
        for (int nt = 0; nt < 4; nt++) {
            const short* kfr = kp + (size_t)(a0 + nt * 16) * 256;
            bf16x8 bk0 = *(const bf16x8*)kfr;
            bf16x8 bk1 = *(const bf16x8*)(kfr + 32);
            sv[nt] = __builtin_amdgcn_mfma_f32_16x16x32_bf16(aq0, bk0, sv[nt], 0, 0, 0);
            sv[nt] = __builtin_amdgcn_mfma_f32_16x16x32_bf16(aq1, bk1, sv[nt], 0, 0, 0);
        }
        #pragma unroll
        for (int nt = 0; nt < 4; nt++)
            #pragma unroll
            for (int r = 0; r < 4; r++) sv[nt][r] = __builtin_exp2f(sv[nt][r]);
        #pragma unroll
        for (int r = 0; r < 4; r++)
            lsum[r] += (sv[0][r] + sv[1][r]) + (sv[2][r] + sv[3][r]);
        #pragma unroll
        for (int nt = 0; nt < 4; nt++)
            #pragma unroll
            for (int r = 0; r < 4; r++)
                Ps[quad * 4 + r][nt * 16 + c16] = f2bf_r(sv[nt][r]);
        // PV: P from wave-private LDS (compiler orders via lgkmcnt), V direct from global
        #pragma unroll
        for (int ks = 0; ks < 64; ks += 32) {
            bf16x8 ap = *(const bf16x8*)&Ps[c16][ks + quad * 8];
            #pragma unroll
            for (int dt = 0; dt < 4; dt++) {
                bf16x8 bv = *(const bf16x8*)(vp + (size_t)dt * 16 * SS + a0 + ks);
                o[dt] = __builtin_amdgcn_mfma_f32_16x16x32_bf16(ap, bv, o[dt], 0, 0, 0);
            }
        }
    }
    // full row-sum within each quad's 16 lanes
    #pragma unroll
    for (int off = 1; off < 16; off <<= 1)
        #pragma unroll
        for (int r = 0; r < 4; r++) lsum[r] += __shfl_xor(lsum[r], off);

    // ---- in-block K-half combine over the retired Ps LDS ----
    __syncthreads();                                   // all waves done with Psb
    float (*Ox)[68] = (float (*)[68])&Psb[0][0][0];    // 64x68 fp32 = 17408B <= 18432B
    float* Lx = Lxb;
    short (*Ot)[72] = Otb;
    int base = rq * 16 + quad * 4;
    if (wave >= 4) {
        #pragma unroll
        for (int dt = 0; dt < 4; dt++)
            #pragma unroll
            for (int r = 0; r < 4; r++)
                Ox[base + r][dt * 16 + c16] = o[dt][r];
        if (c16 == 0)
            #pragma unroll
            for (int r = 0; r < 4; r++) Lx[base + r] = lsum[r];
    }
    __syncthreads();
    if (wave < 4) {
        #pragma unroll
        for (int r = 0; r < 4; r++) {
            float rl = __builtin_amdgcn_rcpf(lsum[r] + Lx[base + r]);
            #pragma unroll
            for (int dt = 0; dt < 4; dt++)
                Ot[base + r][dt * 16 + c16] =
                    f2bf_r((o[dt][r] + Ox[base + r][dt * 16 + c16]) * rl);
        }
    }
    __syncthreads();
    {
        int r = tid >> 3, ch = tid & 7;
        int b = bh >> 2, h = bh & 3;
        *(int4*)&Ob[((size_t)(b * SS + q0 + r)) * 256 + h * 64 + ch * 8] =
            *(const int4*)&Ot[r][ch * 8];
    }
}

// ---------- output projection: bf16 GEMM M=8192 N=1024 K=256; BM=128 BN=64, 4/CU ----------
__global__ __launch_bounds__(256) void outproj_kernel(const short* __restrict__ Ob,
                                                      const short* __restrict__ Wo4,
                                                      float* __restrict__ out) {
    __shared__ alignas(16) short As[128][72];
    __shared__ alignas(16) short Bs[64][72];
    int tid = threadIdx.x;
    int wave = tid >> 6, lane = tid & 63, quad = lane >> 4, c16 = lane & 15;
    int m0 = blockIdx.x * 128, n0 = blockIdx.y * 64;

    f32x4 acc[2][4];
    #pragma unroll
    for (int i = 0; i < 2; i++)
        #pragma unroll
        for (int j = 0; j < 4; j++) acc[i][j] = (f32x4){0.f, 0.f, 0.f, 0.f};

    for (int k0 = 0; k0 < 256; k0 += 64) {
        // A: 128 rows x 64 shorts = 1024 int4 -> 4 iters
        #pragma unroll
        for (int i = 0; i < 4; i++) {
            int id = i * 256 + tid, r = id >> 3, ch = id & 7;
            *(int4*)&As[r][ch * 8] =
                *(const int4*)&Ob[(size_t)(m0 + r) * 256 + k0 + ch * 8];
        }
        // B: 64 rows x 64 shorts = 512 int4 -> 2 iters
        #pragma unroll
        for (int i = 0; i < 2; i++) {
            int id = i * 256 + tid, r = id >> 3, ch = id & 7;
            *(int4*)&Bs[r][ch * 8] =
                *(const int4*)&Wo4[(size_t)(n0 + r) * 256 + k0 + ch * 8];
        }
        __syncthreads();
        #pragma unroll
        for (int ks = 0; ks < 64; ks += 32) {
            bf16x8 af[2], bfr[4];
            #pragma unroll
            for (int mt = 0; mt < 2; mt++)
                af[mt] = *(const bf16x8*)&As[wave * 32 + mt * 16 + c16][ks + quad * 8];
            #pragma unroll
            for (int nt = 0; nt < 4; nt++)
                bfr[nt] = *(const bf16x8*)&Bs[nt * 16 + c16][ks + quad * 8];
            #pragma unroll
            for (int mt = 0; mt < 2; mt++)
                #pragma unroll
                for (int nt = 0; nt < 4; nt++)
                    acc[mt][nt] = __builtin_amdgcn_mfma_f32_16x16x32_bf16(
                        af[mt], bfr[nt], acc[mt][nt], 0, 0, 0);
        }
        __syncthreads();
    }
    #pragma unroll
    for (int mt = 0; mt < 2; mt++)
        #pragma unroll
        for (int nt = 0; nt < 4; nt++) {
            int col = n0 + nt * 16 + c16;
            int rowb = m0 + wave * 32 + mt * 16 + quad * 4;
            #pragma unroll
            for (int r = 0; r < 4; r++)
                out[(size_t)(rowb + r) * 1024 + col] = acc[mt][nt][r];
        }
}

extern "C" void kernel_launch(void* const* d_in, const int* in_sizes, int n_in,
                              void* d_out, int out_size, void* d_ws, size_t ws_size,
                              hipStream_t stream) {
    const float* q  = (const float*)d_in[0];
    const float* kv = (const float*)d_in[1];
    const float* Wq = (const float*)d_in[2];
    const float* Wk = (const float*)d_in[3];
    const float* Wv = (const float*)d_in[4];
    const float* Wo = (const float*)d_in[5];
    float* out = (float*)d_out;

    short* Qb    = (short*)d_ws;           // 2097152 bf16
    short* Kb    = Qb + 2097152;           // 2097152
    short* Vt    = Kb + 2097152;           // 2097152 (pre-transposed [b*256+h*64+d][s])
    short* Wall  = Vt + 2097152;           // 786432
    short* Wo4   = Wall + 786432;          // 262144
    float2* RT   = (float2*)(Wo4 + 262144);    // 65536 float2
    short* Ob    = (short*)(RT + 65536);   // 2097152 bf16, [b*2048+s][h*64+d]
    short* Ab    = Ob + 2097152;           // 16777216 bf16: rows 0..8191 q, 8192..16383 kv

    prep_weights<<<9216, 256, 0, stream>>>(q, kv, Wq, Wk, Wv, Wo, Ab, Wall, Wo4, RT);

    proj_kernel<<<dim3(64, 12), 256, 0, stream>>>(Ab, Wall, RT, Qb, Kb, Vt);

    attn_kernel<<<dim3(32, 16), 512, 0, stream>>>(Qb, Kb, Vt, Ob);

    outproj_kernel<<<dim3(64, 16), 256, 0, stream>>>(Ob, Wo4, out);
}

// Round 7
// 193.393 us; speedup vs baseline: 1.4175x; 1.4175x over previous
//
#include <hip/hip_runtime.h>
#include <math.h>

#define SS 2048
#define EE 1024

using bf16x8 = __attribute__((ext_vector_type(8))) short;
using f32x4  = __attribute__((ext_vector_type(4))) float;

// RTNE (prep only, cold)
__device__ inline short f2bf(float x) {
    unsigned u = __builtin_bit_cast(unsigned, x);
    return (short)((u + 0x7fffu + ((u >> 16) & 1u)) >> 16);
}
// round-half-up, 2 VALU
__device__ inline short f2bf_r(float x) {
    return (short)((__builtin_bit_cast(unsigned, x) + 0x8000u) >> 16);
}
// pack 2 floats -> 2 bf16 in one dword: 2 adds + 1 v_perm
__device__ inline unsigned pk_bf16(float a, float b) {
    unsigned ua = __builtin_bit_cast(unsigned, a) + 0x8000u;
    unsigned ub = __builtin_bit_cast(unsigned, b) + 0x8000u;
    return __builtin_amdgcn_perm(ub, ua, 0x07060302u);
}
// async global->LDS, 16B per lane; LDS dest = wave-uniform base + lane*16
__device__ inline void gl16(const short* g, short* l) {
    __builtin_amdgcn_global_load_lds(
        (const __attribute__((address_space(1))) void*)g,
        (__attribute__((address_space(3))) void*)l, 16, 0, 0);
}

// ---------- weight prep + rope table + q/kv fp32->bf16 conversion ----------
__global__ __launch_bounds__(256) void prep_weights(const float* __restrict__ q,
                                                    const float* __restrict__ kv,
                                                    const float* __restrict__ Wq,
                                                    const float* __restrict__ Wk,
                                                    const float* __restrict__ Wv,
                                                    const float* __restrict__ Wo,
                                                    short* __restrict__ Ab,
                                                    short* __restrict__ Wall,
                                                    short* __restrict__ Wo4,
                                                    float2* __restrict__ RT) {
    if (blockIdx.x < 8192) {
        int gt = blockIdx.x * 256 + threadIdx.x;   // 2,097,152 threads x 8 elems
        size_t e0 = (size_t)gt * 8;
        const float* src = (e0 < 8388608) ? (q + e0) : (kv + (e0 - 8388608));
        float4 v0 = *(const float4*)src;
        float4 v1 = *(const float4*)(src + 4);
        int4 u;
        u.x = pk_bf16(v0.x, v0.y);
        u.y = pk_bf16(v0.z, v0.w);
        u.z = pk_bf16(v1.x, v1.y);
        u.w = pk_bf16(v1.z, v1.w);
        *(int4*)&Ab[e0] = u;
        return;
    }
    int idx = (blockIdx.x - 8192) * 256 + threadIdx.x;   // 262144 = 256 c * 1024 e
    int c = idx >> 10, e = idx & 1023;
    int h = c >> 6, d = c & 63;
    const float* p = Wq + (size_t)e * 1024 + h * 256 + d;   // Wq[e][h*4+g][d]
    Wall[(size_t)c * 1024 + e] = f2bf(0.18033688011112042f * (p[0] + p[64] + p[128] + p[192]));
    Wall[(size_t)(256 + c) * 1024 + e] = f2bf(Wk[(size_t)e * 256 + c]);
    Wall[(size_t)(512 + c) * 1024 + e] = f2bf(Wv[(size_t)e * 256 + c]);
    Wo4[(size_t)e * 256 + c] = f2bf(0.25f * Wo[(size_t)d * 1024 + e]);
    if (idx < 65536) {
        int s = idx >> 5, ii = idx & 31;
        float freq = __expf(-(float)ii * (9.210340371976184f / 32.0f));
        float sn, cs;
        sincosf((float)s * freq, &sn, &cs);
        RT[idx] = (float2){cs, sn};
    }
}

// ---------- fused Q/K/V projection; pure bf16 GEMM w/ global_load_lds staging ----------
// BM=128, BN=64, BK=64; linear LDS (m97 structure); rope/V epilogues on retired LDS.
__global__ __launch_bounds__(256) void proj_kernel(const short* __restrict__ Ab,
                                                   const short* __restrict__ Wall,
                                                   const float2* __restrict__ RT,
                                                   short* __restrict__ Qb,
                                                   short* __restrict__ Kb,
                                                   short* __restrict__ Vt) {
    __shared__ alignas(16) short SMEM[128 * 64 + 64 * 64];   // As[128][64] | Bs[64][64]
    short (*As)[64] = (short (*)[64])SMEM;
    short (*Bs)[64] = (short (*)[64])(SMEM + 128 * 64);
    int tid = threadIdx.x;
    int wave = tid >> 6, lane = tid & 63, quad = lane >> 4, c16 = lane & 15;
    int wm = wave >> 1, wn = wave & 1;
    int m0 = blockIdx.x * 128, n0 = blockIdx.y * 64;
    const short* A = Ab + ((n0 < 256) ? 0 : (size_t)8388608);   // q rows | kv rows

    int lr = lane >> 3, lc = lane & 7;     // lane -> (row-in-8, 16B-chunk)
    f32x4 acc[4][2];
    #pragma unroll
    for (int i = 0; i < 4; i++)
        #pragma unroll
        for (int j = 0; j < 2; j++) acc[i][j] = (f32x4){0.f, 0.f, 0.f, 0.f};

    for (int k0 = 0; k0 < 1024; k0 += 64) {
        __syncthreads();   // prev tile's ds_reads complete
        // A tile: 128x64 bf16 = 16KB -> 16 wave-segments of 1KB; wave handles 4
        #pragma unroll
        for (int i = 0; i < 4; i++) {
            int seg = wave * 4 + i;
            int r = seg * 8 + lr;
            gl16(&A[(size_t)(m0 + r) * 1024 + k0 + lc * 8], &As[seg * 8][0]);
        }
        // B tile: 64x64 bf16 = 8KB -> 8 segments; wave handles 2
        #pragma unroll
        for (int i = 0; i < 2; i++) {
            int seg = wave * 2 + i;
            int r = seg * 8 + lr;
            gl16(&Wall[(size_t)(n0 + r) * 1024 + k0 + lc * 8], &Bs[seg * 8][0]);
        }
        __syncthreads();   // vmcnt(0) drained: tile ready
        #pragma unroll
        for (int ks = 0; ks < 64; ks += 32) {
            bf16x8 af[4], bfr[2];
            #pragma unroll
            for (int mt = 0; mt < 4; mt++)
                af[mt] = *(const bf16x8*)&As[wm * 64 + mt * 16 + c16][ks + quad * 8];
            #pragma unroll
            for (int nt = 0; nt < 2; nt++)
                bfr[nt] = *(const bf16x8*)&Bs[wn * 32 + nt * 16 + c16][ks + quad * 8];
            #pragma unroll
            for (int mt = 0; mt < 4; mt++)
                #pragma unroll
                for (int nt = 0; nt < 2; nt++)
                    acc[mt][nt] = __builtin_amdgcn_mfma_f32_16x16x32_bf16(
                        af[mt], bfr[nt], acc[mt][nt], 0, 0, 0);
        }
    }
    __syncthreads();   // all MFMA LDS reads done before epilogue reuses SMEM
    if (n0 < 512) {
        // Q or K: rope in regs -> As[128][64] bf16 -> coalesced row-major stores
        #pragma unroll
        for (int mt = 0; mt < 4; mt++) {
            #pragma unroll
            for (int nt = 0; nt < 2; nt++) {
                int cl = wn * 32 + nt * 16 + c16;       // local col 0..63
                int ii = cl >> 1;                        // n0 multiple of 64
                float sgn = (lane & 1) ? 1.0f : -1.0f;
                f32x4 v = acc[mt][nt];
                #pragma unroll
                for (int r = 0; r < 4; r++) {
                    int rl = wm * 64 + mt * 16 + quad * 4 + r;   // local row
                    float2 cs = RT[((m0 + rl) & (SS - 1)) * 32 + ii];
                    float other = __shfl_xor(v[r], 1);
                    As[rl][cl] = f2bf_r(v[r] * cs.x + sgn * cs.y * other);
                }
            }
        }
        __syncthreads();
        short* dstb = (n0 < 256) ? Qb : Kb;
        int nc0 = n0 & 255;
        #pragma unroll
        for (int i = 0; i < 4; i++) {
            int id = i * 256 + tid, r = id >> 3, ch = id & 7;
            *(int4*)&dstb[(size_t)(m0 + r) * 256 + nc0 + ch * 8] =
                *(const int4*)&As[r][ch * 8];
        }
    } else {
        // V: transpose via LDS -> Vt[(b*256+c)][s] coalesced along s
        short (*Lt)[136] = (short(*)[136])SMEM;    // 64 c x (128 s + pad) = 17408B <= 24576B
        #pragma unroll
        for (int mt = 0; mt < 4; mt++) {
            #pragma unroll
            for (int nt = 0; nt < 2; nt++) {
                int cl = wn * 32 + nt * 16 + c16;
                int sl = wm * 64 + mt * 16 + quad * 4;
                f32x4 v = acc[mt][nt];
                uint2 u;
                u.x = pk_bf16(v[0], v[1]);
                u.y = pk_bf16(v[2], v[3]);
                *(uint2*)&Lt[cl][sl] = u;
            }
        }
        __syncthreads();
        int b = m0 >> 11, s0 = m0 & (SS - 1), c0 = n0 - 512;
        #pragma unroll
        for (int i = 0; i < 4; i++) {
            int id = i * 256 + tid, c = id >> 4, ch = id & 15;
            *(int4*)&Vt[((size_t)(b * 256 + c0 + c)) * SS + s0 + ch * 8] =
                *(const int4*)&Lt[c][ch * 8];
        }
    }
}

// ---------- MFMA flash attention: R5 structure + XOR-swizzled unpadded LDS + setprio ----------
// 8 waves: wave = (rq = wave&3 -> 16-row q slice, kh = wave>>2 -> K half of 1024 keys).
// K/V/P tiles are [64]-short rows with col ^= ((row&7)<<3) swizzle on BOTH write and read.
// In-block kh-combine in LDS at the end; output bf16 Ob[b,s,h*64+d].
__global__ __launch_bounds__(512, 4) void attn_kernel(const short* __restrict__ Qb,
                                                      const short* __restrict__ Kb,
                                                      const short* __restrict__ Vt,
                                                      short* __restrict__ Ob) {
    // 49152 B carve: Qs[64][64] | Ps2[64][64] | Ks[2][64][64] | Vs[2][64][64]
    __shared__ alignas(16) short SM[24576];
    short (*Qs)[64] = (short (*)[64])SM;                       // byte 0,     8192B
    short (*Ps2)[64] = (short (*)[64])(SM + 4096);             // byte 8192,  8192B
    short (*Ks)[64][64] = (short (*)[64][64])(SM + 8192);      // byte 16384, 16384B
    short (*Vs)[64][64] = (short (*)[64][64])(SM + 16384);     // byte 32768, 16384B
    int tid = threadIdx.x;
    int wave = tid >> 6, lane = tid & 63, quad = lane >> 4, c16 = lane & 15;
    int rq = wave & 3, kh = wave >> 2;
    int qt = blockIdx.x, bh = blockIdx.y;
    int q0 = qt * 64;
    size_t qkbase = (size_t)(bh >> 2) * SS * 256 + (bh & 3) * 64;
    size_t vtbase = (size_t)(bh * 64) * SS;

    {
        int r = tid >> 3, ch = tid & 7;
        *(int4*)&Qs[r][ch * 8] = *(const int4*)&Qb[qkbase + (size_t)(q0 + r) * 256 + ch * 8];
    }
    __syncthreads();
    // one-time Q fragment loads (linear; Qs rows die after this and become kh=0 P tiles)
    bf16x8 aq0 = *(const bf16x8*)&Qs[rq * 16 + c16][quad * 8];
    bf16x8 aq1 = *(const bf16x8*)&Qs[rq * 16 + c16][32 + quad * 8];
    short (*Ps)[64] = (kh == 0) ? (short (*)[64])Qs[rq * 16] : (short (*)[64])Ps2[rq * 16];

    int swz = (c16 & 7) << 3;   // read-side XOR; all tile reads use row = (...)+c16

    float lsum[4] = {0.f, 0.f, 0.f, 0.f};
    f32x4 o[4];
    #pragma unroll
    for (int dt = 0; dt < 4; dt++) o[dt] = (f32x4){0.f, 0.f, 0.f, 0.f};

    int sr = tid >> 3, sch = tid & 7;        // staging: 512 thr = 64 rows x 8 int4
    int wsz = (sch * 8) ^ ((sr & 7) << 3);   // write-side swizzled col base
    // prefetch kt=0 into registers
    int4 kr0 = *(const int4*)&Kb[qkbase + (size_t)sr * 256 + sch * 8];
    int4 kr1 = *(const int4*)&Kb[qkbase + (size_t)(1024 + sr) * 256 + sch * 8];
    int4 vr0 = *(const int4*)&Vt[vtbase + (size_t)sr * SS + sch * 8];
    int4 vr1 = *(const int4*)&Vt[vtbase + (size_t)sr * SS + 1024 + sch * 8];

    for (int kt = 0; kt < 16; kt++) {
        __syncthreads();   // all waves done reading previous Ks/Vs
        *(int4*)&Ks[0][sr][wsz] = kr0;
        *(int4*)&Ks[1][sr][wsz] = kr1;
        *(int4*)&Vs[0][sr][wsz] = vr0;
        *(int4*)&Vs[1][sr][wsz] = vr1;
        if (kt < 15) {   // issue next-tile loads; latency hides under QK/exp/PV below
            int a1 = (kt + 1) * 64;
            kr0 = *(const int4*)&Kb[qkbase + (size_t)(a1 + sr) * 256 + sch * 8];
            kr1 = *(const int4*)&Kb[qkbase + (size_t)(1024 + a1 + sr) * 256 + sch * 8];
            vr0 = *(const int4*)&Vt[vtbase + (size_t)sr * SS + a1 + sch * 8];
            vr1 = *(const int4*)&Vt[vtbase + (size_t)sr * SS + 1024 + a1 + sch * 8];
        }
        __syncthreads();
        f32x4 sv[4];
        #pragma unroll
        for (int nt = 0; nt < 4; nt++) sv[nt] = (f32x4){0.f, 0.f, 0.f, 0.f};
        __builtin_amdgcn_s_setprio(1);
        #pragma unroll
        for (int nt = 0; nt < 4; nt++) {
            bf16x8 bk0 = *(const bf16x8*)&Ks[kh][nt * 16 + c16][(quad * 8) ^ swz];
            bf16x8 bk1 = *(const bf16x8*)&Ks[kh][nt * 16 + c16][(32 + quad * 8) ^ swz];
            sv[nt] = __builtin_amdgcn_mfma_f32_16x16x32_bf16(aq0, bk0, sv[nt], 0, 0, 0);
            sv[nt] = __builtin_amdgcn_mfma_f32_16x16x32_bf16(aq1, bk1, sv[nt], 0, 0, 0);
        }
        __builtin_amdgcn_s_setprio(0);
        #pragma unroll
        for (int nt = 0; nt < 4; nt++)
            #pragma unroll
            for (int r = 0; r < 4; r++) sv[nt][r] = __builtin_exp2f(sv[nt][r]);
        #pragma unroll
        for (int r = 0; r < 4; r++)
            lsum[r] += (sv[0][r] + sv[1][r]) + (sv[2][r] + sv[3][r]);
        #pragma unroll
        for (int nt = 0; nt < 4; nt++)
            #pragma unroll
            for (int r = 0; r < 4; r++) {
                int lrow = quad * 4 + r;
                Ps[lrow][(nt * 16 + c16) ^ ((lrow & 7) << 3)] = f2bf_r(sv[nt][r]);
            }
        #pragma unroll
        for (int ks = 0; ks < 64; ks += 32) {
            bf16x8 ap = *(const bf16x8*)&Ps[c16][(ks + quad * 8) ^ swz];
            __builtin_amdgcn_s_setprio(1);
            #pragma unroll
            for (int dt = 0; dt < 4; dt++) {
                bf16x8 bv = *(const bf16x8*)&Vs[kh][dt * 16 + c16][(ks + quad * 8) ^ swz];
                o[dt] = __builtin_amdgcn_mfma_f32_16x16x32_bf16(ap, bv, o[dt], 0, 0, 0);
            }
            __builtin_amdgcn_s_setprio(0);
        }
    }
    // full row-sum within each quad's 16 lanes
    #pragma unroll
    for (int off = 1; off < 16; off <<= 1)
        #pragma unroll
        for (int r = 0; r < 4; r++) lsum[r] += __shfl_xor(lsum[r], off);

    // ---- in-block K-half combine over the retired LDS pool ----
    __syncthreads();                                 // all waves done with P/K/V tiles
    float (*Ox)[68] = (float (*)[68])SM;             // bytes [0, 17408)
    float* Lx = (float*)(SM + 9216);                 // bytes [18432, 18688)
    short (*Ot)[72] = (short (*)[72])(SM + 12288);   // bytes [24576, 33792)
    int base = rq * 16 + quad * 4;
    if (wave >= 4) {
        #pragma unroll
        for (int dt = 0; dt < 4; dt++)
            #pragma unroll
            for (int r = 0; r < 4; r++)
                Ox[base + r][dt * 16 + c16] = o[dt][r];
        if (c16 == 0)
            #pragma unroll
            for (int r = 0; r < 4; r++) Lx[base + r] = lsum[r];
    }
    __syncthreads();
    if (wave < 4) {
        #pragma unroll
        for (int r = 0; r < 4; r++) {
            float rl = __builtin_amdgcn_rcpf(lsum[r] + Lx[base + r]);
            #pragma unroll
            for (int dt = 0; dt < 4; dt++)
                Ot[base + r][dt * 16 + c16] =
                    f2bf_r((o[dt][r] + Ox[base + r][dt * 16 + c16]) * rl);
        }
    }
    __syncthreads();
    {
        int r = tid >> 3, ch = tid & 7;
        int b = bh >> 2, h = bh & 3;
        *(int4*)&Ob[((size_t)(b * SS + q0 + r)) * 256 + h * 64 + ch * 8] =
            *(const int4*)&Ot[r][ch * 8];
    }
}

// ---------- output projection: bf16 GEMM M=8192 N=1024 K=256; BM=128 BN=64, 4/CU ----------
__global__ __launch_bounds__(256) void outproj_kernel(const short* __restrict__ Ob,
                                                      const short* __restrict__ Wo4,
                                                      float* __restrict__ out) {
    __shared__ alignas(16) short As[128][72];
    __shared__ alignas(16) short Bs[64][72];
    int tid = threadIdx.x;
    int wave = tid >> 6, lane = tid & 63, quad = lane >> 4, c16 = lane & 15;
    int m0 = blockIdx.x * 128, n0 = blockIdx.y * 64;

    f32x4 acc[2][4];
    #pragma unroll
    for (int i = 0; i < 2; i++)
        #pragma unroll
        for (int j = 0; j < 4; j++) acc[i][j] = (f32x4){0.f, 0.f, 0.f, 0.f};

    for (int k0 = 0; k0 < 256; k0 += 64) {
        // A: 128 rows x 64 shorts = 1024 int4 -> 4 iters
        #pragma unroll
        for (int i = 0; i < 4; i++) {
            int id = i * 256 + tid, r = id >> 3, ch = id & 7;
            *(int4*)&As[r][ch * 8] =
                *(const int4*)&Ob[(size_t)(m0 + r) * 256 + k0 + ch * 8];
        }
        // B: 64 rows x 64 shorts = 512 int4 -> 2 iters
        #pragma unroll
        for (int i = 0; i < 2; i++) {
            int id = i * 256 + tid, r = id >> 3, ch = id & 7;
            *(int4*)&Bs[r][ch * 8] =
                *(const int4*)&Wo4[(size_t)(n0 + r) * 256 + k0 + ch * 8];
        }
        __syncthreads();
        #pragma unroll
        for (int ks = 0; ks < 64; ks += 32) {
            bf16x8 af[2], bfr[4];
            #pragma unroll
            for (int mt = 0; mt < 2; mt++)
                af[mt] = *(const bf16x8*)&As[wave * 32 + mt * 16 + c16][ks + quad * 8];
            #pragma unroll
            for (int nt = 0; nt < 4; nt++)
                bfr[nt] = *(const bf16x8*)&Bs[nt * 16 + c16][ks + quad * 8];
            #pragma unroll
            for (int mt = 0; mt < 2; mt++)
                #pragma unroll
                for (int nt = 0; nt < 4; nt++)
                    acc[mt][nt] = __builtin_amdgcn_mfma_f32_16x16x32_bf16(
                        af[mt], bfr[nt], acc[mt][nt], 0, 0, 0);
        }
        __syncthreads();
    }
    #pragma unroll
    for (int mt = 0; mt < 2; mt++)
        #pragma unroll
        for (int nt = 0; nt < 4; nt++) {
            int col = n0 + nt * 16 + c16;
            int rowb = m0 + wave * 32 + mt * 16 + quad * 4;
            #pragma unroll
            for (int r = 0; r < 4; r++)
                out[(size_t)(rowb + r) * 1024 + col] = acc[mt][nt][r];
        }
}

extern "C" void kernel_launch(void* const* d_in, const int* in_sizes, int n_in,
                              void* d_out, int out_size, void* d_ws, size_t ws_size,
                              hipStream_t stream) {
    const float* q  = (const float*)d_in[0];
    const float* kv = (const float*)d_in[1];
    const float* Wq = (const float*)d_in[2];
    const float* Wk = (const float*)d_in[3];
    const float* Wv = (const float*)d_in[4];
    const float* Wo = (const float*)d_in[5];
    float* out = (float*)d_out;

    short* Qb    = (short*)d_ws;           // 2097152 bf16
    short* Kb    = Qb + 2097152;           // 2097152
    short* Vt    = Kb + 2097152;           // 2097152 (pre-transposed [b*256+h*64+d][s])
    short* Wall  = Vt + 2097152;           // 786432
    short* Wo4   = Wall + 786432;          // 262144
    float2* RT   = (float2*)(Wo4 + 262144);    // 65536 float2
    short* Ob    = (short*)(RT + 65536);   // 2097152 bf16, [b*2048+s][h*64+d]
    short* Ab    = Ob + 2097152;           // 16777216 bf16: rows 0..8191 q, 8192..16383 kv

    prep_weights<<<9216, 256, 0, stream>>>(q, kv, Wq, Wk, Wv, Wo, Ab, Wall, Wo4, RT);

    proj_kernel<<<dim3(64, 12), 256, 0, stream>>>(Ab, Wall, RT, Qb, Kb, Vt);

    attn_kernel<<<dim3(32, 16), 512, 0, stream>>>(Qb, Kb, Vt, Ob);

    outproj_kernel<<<dim3(64, 16), 256, 0, stream>>>(Ob, Wo4, out);
}

// Round 8
// 191.608 us; speedup vs baseline: 1.4307x; 1.0093x over previous
//
#include <hip/hip_runtime.h>
#include <math.h>

#define SS 2048
#define EE 1024

using bf16x8 = __attribute__((ext_vector_type(8))) short;
using f32x4  = __attribute__((ext_vector_type(4))) float;

// RTNE (prep only, cold)
__device__ inline short f2bf(float x) {
    unsigned u = __builtin_bit_cast(unsigned, x);
    return (short)((u + 0x7fffu + ((u >> 16) & 1u)) >> 16);
}
// round-half-up, 2 VALU
__device__ inline short f2bf_r(float x) {
    return (short)((__builtin_bit_cast(unsigned, x) + 0x8000u) >> 16);
}
// pack 2 floats -> 2 bf16 in one dword: 2 adds + 1 v_perm
__device__ inline unsigned pk_bf16(float a, float b) {
    unsigned ua = __builtin_bit_cast(unsigned, a) + 0x8000u;
    unsigned ub = __builtin_bit_cast(unsigned, b) + 0x8000u;
    return __builtin_amdgcn_perm(ub, ua, 0x07060302u);
}
// async global->LDS, 16B per lane; LDS dest = wave-uniform base + lane*16
__device__ inline void gl16(const short* g, short* l) {
    __builtin_amdgcn_global_load_lds(
        (const __attribute__((address_space(1))) void*)g,
        (__attribute__((address_space(3))) void*)l, 16, 0, 0);
}

// ---------- weight prep + rope table + q/kv fp32->bf16 conversion ----------
__global__ __launch_bounds__(256) void prep_weights(const float* __restrict__ q,
                                                    const float* __restrict__ kv,
                                                    const float* __restrict__ Wq,
                                                    const float* __restrict__ Wk,
                                                    const float* __restrict__ Wv,
                                                    const float* __restrict__ Wo,
                                                    short* __restrict__ Ab,
                                                    short* __restrict__ Wall,
                                                    short* __restrict__ Wo4,
                                                    float2* __restrict__ RT) {
    if (blockIdx.x < 8192) {
        int gt = blockIdx.x * 256 + threadIdx.x;   // 2,097,152 threads x 8 elems
        size_t e0 = (size_t)gt * 8;
        const float* src = (e0 < 8388608) ? (q + e0) : (kv + (e0 - 8388608));
        float4 v0 = *(const float4*)src;
        float4 v1 = *(const float4*)(src + 4);
        int4 u;
        u.x = pk_bf16(v0.x, v0.y);
        u.y = pk_bf16(v0.z, v0.w);
        u.z = pk_bf16(v1.x, v1.y);
        u.w = pk_bf16(v1.z, v1.w);
        *(int4*)&Ab[e0] = u;
        return;
    }
    int idx = (blockIdx.x - 8192) * 256 + threadIdx.x;   // 262144 = 256 c * 1024 e
    int c = idx >> 10, e = idx & 1023;
    int h = c >> 6, d = c & 63;
    const float* p = Wq + (size_t)e * 1024 + h * 256 + d;   // Wq[e][h*4+g][d]
    Wall[(size_t)c * 1024 + e] = f2bf(0.18033688011112042f * (p[0] + p[64] + p[128] + p[192]));
    Wall[(size_t)(256 + c) * 1024 + e] = f2bf(Wk[(size_t)e * 256 + c]);
    Wall[(size_t)(512 + c) * 1024 + e] = f2bf(Wv[(size_t)e * 256 + c]);
    Wo4[(size_t)e * 256 + c] = f2bf(0.25f * Wo[(size_t)d * 1024 + e]);
    if (idx < 65536) {
        int s = idx >> 5, ii = idx & 31;
        float freq = __expf(-(float)ii * (9.210340371976184f / 32.0f));
        float sn, cs;
        sincosf((float)s * freq, &sn, &cs);
        RT[idx] = (float2){cs, sn};
    }
}

// ---------- fused Q/K/V projection; pure bf16 GEMM w/ global_load_lds staging ----------
// BM=128, BN=64, BK=64; linear LDS (m97 structure); rope/V epilogues on retired LDS.
__global__ __launch_bounds__(256) void proj_kernel(const short* __restrict__ Ab,
                                                   const short* __restrict__ Wall,
                                                   const float2* __restrict__ RT,
                                                   short* __restrict__ Qb,
                                                   short* __restrict__ Kb,
                                                   short* __restrict__ Vt) {
    __shared__ alignas(16) short SMEM[128 * 64 + 64 * 64];   // As[128][64] | Bs[64][64]
    short (*As)[64] = (short (*)[64])SMEM;
    short (*Bs)[64] = (short (*)[64])(SMEM + 128 * 64);
    int tid = threadIdx.x;
    int wave = tid >> 6, lane = tid & 63, quad = lane >> 4, c16 = lane & 15;
    int wm = wave >> 1, wn = wave & 1;
    int m0 = blockIdx.x * 128, n0 = blockIdx.y * 64;
    const short* A = Ab + ((n0 < 256) ? 0 : (size_t)8388608);   // q rows | kv rows

    int lr = lane >> 3, lc = lane & 7;     // lane -> (row-in-8, 16B-chunk)
    f32x4 acc[4][2];
    #pragma unroll
    for (int i = 0; i < 4; i++)
        #pragma unroll
        for (int j = 0; j < 2; j++) acc[i][j] = (f32x4){0.f, 0.f, 0.f, 0.f};

    for (int k0 = 0; k0 < 1024; k0 += 64) {
        __syncthreads();   // prev tile's ds_reads complete
        // A tile: 128x64 bf16 = 16KB -> 16 wave-segments of 1KB; wave handles 4
        #pragma unroll
        for (int i = 0; i < 4; i++) {
            int seg = wave * 4 + i;
            int r = seg * 8 + lr;
            gl16(&A[(size_t)(m0 + r) * 1024 + k0 + lc * 8], &As[seg * 8][0]);
        }
        // B tile: 64x64 bf16 = 8KB -> 8 segments; wave handles 2
        #pragma unroll
        for (int i = 0; i < 2; i++) {
            int seg = wave * 2 + i;
            int r = seg * 8 + lr;
            gl16(&Wall[(size_t)(n0 + r) * 1024 + k0 + lc * 8], &Bs[seg * 8][0]);
        }
        __syncthreads();   // vmcnt(0) drained: tile ready
        #pragma unroll
        for (int ks = 0; ks < 64; ks += 32) {
            bf16x8 af[4], bfr[2];
            #pragma unroll
            for (int mt = 0; mt < 4; mt++)
                af[mt] = *(const bf16x8*)&As[wm * 64 + mt * 16 + c16][ks + quad * 8];
            #pragma unroll
            for (int nt = 0; nt < 2; nt++)
                bfr[nt] = *(const bf16x8*)&Bs[wn * 32 + nt * 16 + c16][ks + quad * 8];
            #pragma unroll
            for (int mt = 0; mt < 4; mt++)
                #pragma unroll
                for (int nt = 0; nt < 2; nt++)
                    acc[mt][nt] = __builtin_amdgcn_mfma_f32_16x16x32_bf16(
                        af[mt], bfr[nt], acc[mt][nt], 0, 0, 0);
        }
    }
    __syncthreads();   // all MFMA LDS reads done before epilogue reuses SMEM
    if (n0 < 512) {
        // Q or K: rope in regs -> As[128][64] bf16 -> coalesced row-major stores
        #pragma unroll
        for (int mt = 0; mt < 4; mt++) {
            #pragma unroll
            for (int nt = 0; nt < 2; nt++) {
                int cl = wn * 32 + nt * 16 + c16;       // local col 0..63
                int ii = cl >> 1;                        // n0 multiple of 64
                float sgn = (lane & 1) ? 1.0f : -1.0f;
                f32x4 v = acc[mt][nt];
                #pragma unroll
                for (int r = 0; r < 4; r++) {
                    int rl = wm * 64 + mt * 16 + quad * 4 + r;   // local row
                    float2 cs = RT[((m0 + rl) & (SS - 1)) * 32 + ii];
                    float other = __shfl_xor(v[r], 1);
                    As[rl][cl] = f2bf_r(v[r] * cs.x + sgn * cs.y * other);
                }
            }
        }
        __syncthreads();
        short* dstb = (n0 < 256) ? Qb : Kb;
        int nc0 = n0 & 255;
        #pragma unroll
        for (int i = 0; i < 4; i++) {
            int id = i * 256 + tid, r = id >> 3, ch = id & 7;
            *(int4*)&dstb[(size_t)(m0 + r) * 256 + nc0 + ch * 8] =
                *(const int4*)&As[r][ch * 8];
        }
    } else {
        // V: transpose via LDS -> Vt[(b*256+c)][s] coalesced along s
        short (*Lt)[136] = (short(*)[136])SMEM;    // 64 c x (128 s + pad) = 17408B <= 24576B
        #pragma unroll
        for (int mt = 0; mt < 4; mt++) {
            #pragma unroll
            for (int nt = 0; nt < 2; nt++) {
                int cl = wn * 32 + nt * 16 + c16;
                int sl = wm * 64 + mt * 16 + quad * 4;
                f32x4 v = acc[mt][nt];
                uint2 u;
                u.x = pk_bf16(v[0], v[1]);
                u.y = pk_bf16(v[2], v[3]);
                *(uint2*)&Lt[cl][sl] = u;
            }
        }
        __syncthreads();
        int b = m0 >> 11, s0 = m0 & (SS - 1), c0 = n0 - 512;
        #pragma unroll
        for (int i = 0; i < 4; i++) {
            int id = i * 256 + tid, c = id >> 4, ch = id & 15;
            *(int4*)&Vt[((size_t)(b * 256 + c0 + c)) * SS + s0 + ch * 8] =
                *(const int4*)&Lt[c][ch * 8];
        }
    }
}

// ---------- MFMA flash attention: swizzled LDS + setprio + 2-DEEP register prefetch ----------
// 8 waves: wave = (rq = wave&3 -> 16-row q slice, kh = wave>>2 -> K half of 1024 keys).
// K/V/P tiles are [64]-short rows with col ^= ((row&7)<<3) swizzle on write and read.
// kt loop unrolled by 2 with two named prefetch register sets (A,B): loads for tile
// kt+2 are issued at tile kt -> ~2 compute phases of latency slack (HBM-miss class).
// In-block kh-combine in LDS at the end; output bf16 Ob[b,s,h*64+d].
__global__ __launch_bounds__(512, 4) void attn_kernel(const short* __restrict__ Qb,
                                                      const short* __restrict__ Kb,
                                                      const short* __restrict__ Vt,
                                                      short* __restrict__ Ob) {
    // 49152 B carve: Qs[64][64] | Ps2[64][64] | Ks[2][64][64] | Vs[2][64][64]
    __shared__ alignas(16) short SM[24576];
    short (*Qs)[64] = (short (*)[64])SM;                       // byte 0,     8192B
    short (*Ps2)[64] = (short (*)[64])(SM + 4096);             // byte 8192,  8192B
    short (*Ks)[64][64] = (short (*)[64][64])(SM + 8192);      // byte 16384, 16384B
    short (*Vs)[64][64] = (short (*)[64][64])(SM + 16384);     // byte 32768, 16384B
    int tid = threadIdx.x;
    int wave = tid >> 6, lane = tid & 63, quad = lane >> 4, c16 = lane & 15;
    int rq = wave & 3, kh = wave >> 2;
    int qt = blockIdx.x, bh = blockIdx.y;
    int q0 = qt * 64;
    size_t qkbase = (size_t)(bh >> 2) * SS * 256 + (bh & 3) * 64;
    size_t vtbase = (size_t)(bh * 64) * SS;

    {
        int r = tid >> 3, ch = tid & 7;
        *(int4*)&Qs[r][ch * 8] = *(const int4*)&Qb[qkbase + (size_t)(q0 + r) * 256 + ch * 8];
    }
    __syncthreads();
    // one-time Q fragment loads (linear; Qs rows die after this and become kh=0 P tiles)
    bf16x8 aq0 = *(const bf16x8*)&Qs[rq * 16 + c16][quad * 8];
    bf16x8 aq1 = *(const bf16x8*)&Qs[rq * 16 + c16][32 + quad * 8];
    short (*Ps)[64] = (kh == 0) ? (short (*)[64])Qs[rq * 16] : (short (*)[64])Ps2[rq * 16];

    int swz = (c16 & 7) << 3;   // read-side XOR; all tile reads use row = (...)+c16

    float lsum[4] = {0.f, 0.f, 0.f, 0.f};
    f32x4 o[4];
    #pragma unroll
    for (int dt = 0; dt < 4; dt++) o[dt] = (f32x4){0.f, 0.f, 0.f, 0.f};

    int sr = tid >> 3, sch = tid & 7;        // staging: 512 thr = 64 rows x 8 int4
    int wsz = (sch * 8) ^ ((sr & 7) << 3);   // write-side swizzled col base
    const short* kbase = Kb + qkbase;
    const short* vbase = Vt + vtbase + (size_t)sr * SS;

    // 2-deep prefetch register sets: A holds tile kt, B holds tile kt+1
    int4 kA0 = *(const int4*)&kbase[(size_t)(0 + sr) * 256 + sch * 8];
    int4 kA1 = *(const int4*)&kbase[(size_t)(1024 + 0 + sr) * 256 + sch * 8];
    int4 vA0 = *(const int4*)&vbase[0 + sch * 8];
    int4 vA1 = *(const int4*)&vbase[1024 + 0 + sch * 8];
    int4 kB0 = *(const int4*)&kbase[(size_t)(64 + sr) * 256 + sch * 8];
    int4 kB1 = *(const int4*)&kbase[(size_t)(1024 + 64 + sr) * 256 + sch * 8];
    int4 vB0 = *(const int4*)&vbase[64 + sch * 8];
    int4 vB1 = *(const int4*)&vbase[1024 + 64 + sch * 8];

    auto compute_tile = [&]() {
        f32x4 sv[4];
        #pragma unroll
        for (int nt = 0; nt < 4; nt++) sv[nt] = (f32x4){0.f, 0.f, 0.f, 0.f};
        __builtin_amdgcn_s_setprio(1);
        #pragma unroll
        for (int nt = 0; nt < 4; nt++) {
            bf16x8 bk0 = *(const bf16x8*)&Ks[kh][nt * 16 + c16][(quad * 8) ^ swz];
            bf16x8 bk1 = *(const bf16x8*)&Ks[kh][nt * 16 + c16][(32 + quad * 8) ^ swz];
            sv[nt] = __builtin_amdgcn_mfma_f32_16x16x32_bf16(aq0, bk0, sv[nt], 0, 0, 0);
            sv[nt] = __builtin_amdgcn_mfma_f32_16x16x32_bf16(aq1, bk1, sv[nt], 0, 0, 0);
        }
        __builtin_amdgcn_s_setprio(0);
        #pragma unroll
        for (int nt = 0; nt < 4; nt++)
            #pragma unroll
            for (int r = 0; r < 4; r++) sv[nt][r] = __builtin_exp2f(sv[nt][r]);
        #pragma unroll
        for (int r = 0; r < 4; r++)
            lsum[r] += (sv[0][r] + sv[1][r]) + (sv[2][r] + sv[3][r]);
        #pragma unroll
        for (int nt = 0; nt < 4; nt++)
            #pragma unroll
            for (int r = 0; r < 4; r++) {
                int lrow = quad * 4 + r;
                Ps[lrow][(nt * 16 + c16) ^ ((lrow & 7) << 3)] = f2bf_r(sv[nt][r]);
            }
        #pragma unroll
        for (int ks = 0; ks < 64; ks += 32) {
            bf16x8 ap = *(const bf16x8*)&Ps[c16][(ks + quad * 8) ^ swz];
            __builtin_amdgcn_s_setprio(1);
            #pragma unroll
            for (int dt = 0; dt < 4; dt++) {
                bf16x8 bv = *(const bf16x8*)&Vs[kh][dt * 16 + c16][(ks + quad * 8) ^ swz];
                o[dt] = __builtin_amdgcn_mfma_f32_16x16x32_bf16(ap, bv, o[dt], 0, 0, 0);
            }
            __builtin_amdgcn_s_setprio(0);
        }
    };

    #pragma unroll 1
    for (int kt = 0; kt < 16; kt += 2) {
        // ---- tile kt: write set A, refill A from kt+2 ----
        __syncthreads();   // all waves done reading previous Ks/Vs
        *(int4*)&Ks[0][sr][wsz] = kA0;
        *(int4*)&Ks[1][sr][wsz] = kA1;
        *(int4*)&Vs[0][sr][wsz] = vA0;
        *(int4*)&Vs[1][sr][wsz] = vA1;
        if (kt + 2 < 16) {
            int a1 = (kt + 2) * 64;
            kA0 = *(const int4*)&kbase[(size_t)(a1 + sr) * 256 + sch * 8];
            kA1 = *(const int4*)&kbase[(size_t)(1024 + a1 + sr) * 256 + sch * 8];
            vA0 = *(const int4*)&vbase[a1 + sch * 8];
            vA1 = *(const int4*)&vbase[1024 + a1 + sch * 8];
        }
        __syncthreads();
        compute_tile();
        // ---- tile kt+1: write set B, refill B from kt+3 ----
        __syncthreads();
        *(int4*)&Ks[0][sr][wsz] = kB0;
        *(int4*)&Ks[1][sr][wsz] = kB1;
        *(int4*)&Vs[0][sr][wsz] = vB0;
        *(int4*)&Vs[1][sr][wsz] = vB1;
        if (kt + 3 < 16) {
            int a1 = (kt + 3) * 64;
            kB0 = *(const int4*)&kbase[(size_t)(a1 + sr) * 256 + sch * 8];
            kB1 = *(const int4*)&kbase[(size_t)(1024 + a1 + sr) * 256 + sch * 8];
            vB0 = *(const int4*)&vbase[a1 + sch * 8];
            vB1 = *(const int4*)&vbase[1024 + a1 + sch * 8];
        }
        __syncthreads();
        compute_tile();
    }
    // full row-sum within each quad's 16 lanes
    #pragma unroll
    for (int off = 1; off < 16; off <<= 1)
        #pragma unroll
        for (int r = 0; r < 4; r++) lsum[r] += __shfl_xor(lsum[r], off);

    // ---- in-block K-half combine over the retired LDS pool ----
    __syncthreads();                                 // all waves done with P/K/V tiles
    float (*Ox)[68] = (float (*)[68])SM;             // bytes [0, 17408)
    float* Lx = (float*)(SM + 9216);                 // bytes [18432, 18688)
    short (*Ot)[72] = (short (*)[72])(SM + 12288);   // bytes [24576, 33792)
    int base = rq * 16 + quad * 4;
    if (wave >= 4) {
        #pragma unroll
        for (int dt = 0; dt < 4; dt++)
            #pragma unroll
            for (int r = 0; r < 4; r++)
                Ox[base + r][dt * 16 + c16] = o[dt][r];
        if (c16 == 0)
            #pragma unroll
            for (int r = 0; r < 4; r++) Lx[base + r] = lsum[r];
    }
    __syncthreads();
    if (wave < 4) {
        #pragma unroll
        for (int r = 0; r < 4; r++) {
            float rl = __builtin_amdgcn_rcpf(lsum[r] + Lx[base + r]);
            #pragma unroll
            for (int dt = 0; dt < 4; dt++)
                Ot[base + r][dt * 16 + c16] =
                    f2bf_r((o[dt][r] + Ox[base + r][dt * 16 + c16]) * rl);
        }
    }
    __syncthreads();
    {
        int r = tid >> 3, ch = tid & 7;
        int b = bh >> 2, h = bh & 3;
        *(int4*)&Ob[((size_t)(b * SS + q0 + r)) * 256 + h * 64 + ch * 8] =
            *(const int4*)&Ot[r][ch * 8];
    }
}

// ---------- output projection: bf16 GEMM M=8192 N=1024 K=256; BM=128 BN=64, 4/CU ----------
__global__ __launch_bounds__(256) void outproj_kernel(const short* __restrict__ Ob,
                                                      const short* __restrict__ Wo4,
                                                      float* __restrict__ out) {
    __shared__ alignas(16) short As[128][72];
    __shared__ alignas(16) short Bs[64][72];
    int tid = threadIdx.x;
    int wave = tid >> 6, lane = tid & 63, quad = lane >> 4, c16 = lane & 15;
    int m0 = blockIdx.x * 128, n0 = blockIdx.y * 64;

    f32x4 acc[2][4];
    #pragma unroll
    for (int i = 0; i < 2; i++)
        #pragma unroll
        for (int j = 0; j < 4; j++) acc[i][j] = (f32x4){0.f, 0.f, 0.f, 0.f};

    for (int k0 = 0; k0 < 256; k0 += 64) {
        // A: 128 rows x 64 shorts = 1024 int4 -> 4 iters
        #pragma unroll
        for (int i = 0; i < 4; i++) {
            int id = i * 256 + tid, r = id >> 3, ch = id & 7;
            *(int4*)&As[r][ch * 8] =
                *(const int4*)&Ob[(size_t)(m0 + r) * 256 + k0 + ch * 8];
        }
        // B: 64 rows x 64 shorts = 512 int4 -> 2 iters
        #pragma unroll
        for (int i = 0; i < 2; i++) {
            int id = i * 256 + tid, r = id >> 3, ch = id & 7;
            *(int4*)&Bs[r][ch * 8] =
                *(const int4*)&Wo4[(size_t)(n0 + r) * 256 + k0 + ch * 8];
        }
        __syncthreads();
        #pragma unroll
        for (int ks = 0; ks < 64; ks += 32) {
            bf16x8 af[2], bfr[4];
            #pragma unroll
            for (int mt = 0; mt < 2; mt++)
                af[mt] = *(const bf16x8*)&As[wave * 32 + mt * 16 + c16][ks + quad * 8];
            #pragma unroll
            for (int nt = 0; nt < 4; nt++)
                bfr[nt] = *(const bf16x8*)&Bs[nt * 16 + c16][ks + quad * 8];
            #pragma unroll
            for (int mt = 0; mt < 2; mt++)
                #pragma unroll
                for (int nt = 0; nt < 4; nt++)
                    acc[mt][nt] = __builtin_amdgcn_mfma_f32_16x16x32_bf16(
                        af[mt], bfr[nt], acc[mt][nt], 0, 0, 0);
        }
        __syncthreads();
    }
    #pragma unroll
    for (int mt = 0; mt < 2; mt++)
        #pragma unroll
        for (int nt = 0; nt < 4; nt++) {
            int col = n0 + nt * 16 + c16;
            int rowb = m0 + wave * 32 + mt * 16 + quad * 4;
            #pragma unroll
            for (int r = 0; r < 4; r++)
                out[(size_t)(rowb + r) * 1024 + col] = acc[mt][nt][r];
        }
}

extern "C" void kernel_launch(void* const* d_in, const int* in_sizes, int n_in,
                              void* d_out, int out_size, void* d_ws, size_t ws_size,
                              hipStream_t stream) {
    const float* q  = (const float*)d_in[0];
    const float* kv = (const float*)d_in[1];
    const float* Wq = (const float*)d_in[2];
    const float* Wk = (const float*)d_in[3];
    const float* Wv = (const float*)d_in[4];
    const float* Wo = (const float*)d_in[5];
    float* out = (float*)d_out;

    short* Qb    = (short*)d_ws;           // 2097152 bf16
    short* Kb    = Qb + 2097152;           // 2097152
    short* Vt    = Kb + 2097152;           // 2097152 (pre-transposed [b*256+h*64+d][s])
    short* Wall  = Vt + 2097152;           // 786432
    short* Wo4   = Wall + 786432;          // 262144
    float2* RT   = (float2*)(Wo4 + 262144);    // 65536 float2
    short* Ob    = (short*)(RT + 65536);   // 2097152 bf16, [b*2048+s][h*64+d]
    short* Ab    = Ob + 2097152;           // 16777216 bf16: rows 0..8191 q, 8192..16383 kv

    prep_weights<<<9216, 256, 0, stream>>>(q, kv, Wq, Wk, Wv, Wo, Ab, Wall, Wo4, RT);

    proj_kernel<<<dim3(64, 12), 256, 0, stream>>>(Ab, Wall, RT, Qb, Kb, Vt);

    attn_kernel<<<dim3(32, 16), 512, 0, stream>>>(Qb, Kb, Vt, Ob);

    outproj_kernel<<<dim3(64, 16), 256, 0, stream>>>(Ob, Wo4, out);
}